// Round 12
// baseline (126.585 us; speedup 1.0000x reference)
//
#include <hip/hip_runtime.h>

#define HD 64       // HIDDEN_DIM
#define NE 512      // N_EMBEDS
#define HW 1024     // 32*32 spatial positions per batch image
#define CH_C 4      // c-steps per chunk
#define NCH (HD / CH_C)        // 16 chunks
#define CHUNK_F4 512           // float4 per chunk (4*512 floats = 8 KB)

typedef float f32x2 __attribute__((ext_vector_type(2)));

// ---------------------------------------------------------------------------
// Prep (130 blocks x 256):
//  blk 0..127 : epT[c][k] = -2 * e[k][c]   (bit-exact -2 fold)
//  blk 128/129: esq[k] = np.sum(e[k]*e[k]), numpy pairwise-8, no contraction.
//  Verified absmax==0.0 R1-R11.
// ---------------------------------------------------------------------------
__global__ __launch_bounds__(256) void vq_prep_kernel(const float* __restrict__ e,
                                                      float* __restrict__ epT,
                                                      float* __restrict__ esq) {
  const int blk = blockIdx.x;
  if (blk < 128) {
    const int t = blk * 256 + threadIdx.x;     // 0..32767
    const int c = t >> 9, k = t & 511;
    epT[t] = -2.0f * e[k * HD + c];
  } else {
    const int k = (blk - 128) * 256 + threadIdx.x;   // 0..511
    const float4* __restrict__ rowv = reinterpret_cast<const float4*>(e + k * HD);
    float row[HD];
    #pragma unroll
    for (int i = 0; i < 16; ++i) {
      const float4 v = rowv[i];
      row[4 * i + 0] = v.x; row[4 * i + 1] = v.y;
      row[4 * i + 2] = v.z; row[4 * i + 3] = v.w;
    }
    float result;
    {
      #pragma clang fp contract(off)
      float r[8];
      #pragma unroll
      for (int j = 0; j < 8; ++j) r[j] = row[j] * row[j];
      #pragma unroll
      for (int i = 8; i < HD; i += 8) {
        #pragma unroll
        for (int j = 0; j < 8; ++j) r[j] = r[j] + row[i + j] * row[i + j];
      }
      result = ((r[0] + r[1]) + (r[2] + r[3])) + ((r[4] + r[5]) + (r[6] + r[7]));
    }
    esq[k] = result;
  }
}

// issue one chunk's DMA: 512 float4 over 256 threads = 2 x 16B per thread
__device__ __forceinline__ void dma_chunk(const float4* __restrict__ g4,
                                          float4* buf4, int ch, int t) {
  const float4* src = g4 + (size_t)ch * CHUNK_F4;
  __builtin_amdgcn_global_load_lds(
      (const __attribute__((address_space(1))) void*)(src + t),
      (__attribute__((address_space(3))) void*)(buf4 + t), 16, 0, 0);
  __builtin_amdgcn_global_load_lds(
      (const __attribute__((address_space(1))) void*)(src + 256 + t),
      (__attribute__((address_space(3))) void*)(buf4 + 256 + t), 16, 0, 0);
}

// ---------------------------------------------------------------------------
// Main R12: 2048 blocks x 256 (4 waves). Block = 32 positions x 512 codes.
//
// R11 post-mortem: neither LDS (~41 us model) nor VALU (36 us) saturated;
// the 27 us gap is the chunk loop's vmcnt(0)-drain + barrier serializing the
// 16 KB DMA latency every chunk (m97-style stall). R12 restructures:
// 3-deep ring of 4-c chunks (8 KB each); per chunk: s_waitcnt vmcnt(2)
// (chunk ch landed, ch+1 still in flight) -> raw s_barrier (NO __syncthreads
// -- that would re-emit the vmcnt(0) drain) -> issue DMA(ch+2) into the
// buffer freed at ch-1 -> compute. DMA runs ~2 chunk-times ahead.
// Race-safety: barrier at ch top means all waves consumed buf[(ch-1)%3]
// (ds_read results consumed => retired), so DMA(ch+2) overwrite is safe.
// Last chunk waits vmcnt(0). Everything else identical to R11 (bit-exact).
// LDS: 8 xs + 24 ring + 0.25 = ~33 KB -> 4 blocks/CU kept.
// ---------------------------------------------------------------------------
__global__ __launch_bounds__(256)
__attribute__((amdgpu_waves_per_eu(4, 4)))
void vq_main_kernel(const float* __restrict__ x,
                    const float* __restrict__ epT,
                    const float* __restrict__ esq,
                    const float* __restrict__ e,
                    float* __restrict__ out) {
  __shared__ float xs[HD * 32];        // 8 KB  [c][pos]
  __shared__ float es[3 * CH_C * NE];  // 24 KB ring of 3 x 8 KB chunks
  __shared__ float xsq[32];
  __shared__ int   bcomb[32];

  float* smin = es;                    // [64 slots][32 pos] floats (8 KB) overlay
  int*   sidx = (int*)(es + 64 * 32);  // [64 slots][32 pos] ints   (8 KB) overlay

  const int t    = threadIdx.x;
  const int lane = t & 63;
  const int wc   = t >> 6;             // 0..3  wave = code quarter
  const int p    = lane & 3;           // pos-octet group
  const int q    = lane >> 2;          // 0..15 code slot
  const int posb = p * 8;              // lane's 8 positions
  const int kb   = wc * 128 + q * 8;   // lane's 8 codes

  const int blk = blockIdx.x;          // 2048
  const int b   = blk >> 5;
  const int s0  = (blk & 31) << 5;
  const size_t xbase = (size_t)b * (HD * HW) + s0;

  // ---- stage x into LDS [c][pos] (256 threads x 8 floats, coalesced)
  {
    const int pos = t & 31, cr = t >> 5;        // cr 0..7
    #pragma unroll
    for (int i = 0; i < 8; ++i) {
      const int c = cr + 8 * i;
      xs[c * 32 + pos] = x[xbase + (size_t)c * HW + pos];
    }
  }
  __syncthreads();

  // ---- xsq[pos]: numpy pairwise-8, no contraction (bit-exact)
  if (t < 32) {
    #pragma clang fp contract(off)
    float r[8];
    #pragma unroll
    for (int j = 0; j < 8; ++j) {
      const float v = xs[j * 32 + t];
      r[j] = v * v;
    }
    #pragma unroll
    for (int i = 8; i < HD; i += 8) {
      #pragma unroll
      for (int j = 0; j < 8; ++j) {
        const float v = xs[(i + j) * 32 + t];
        r[j] = r[j] + v * v;
      }
    }
    xsq[t] = ((r[0] + r[1]) + (r[2] + r[3])) + ((r[4] + r[5]) + (r[6] + r[7]));
  }

  // ---- ring-buffered accumulate; DMA 2 chunks ahead
  float4* es4 = reinterpret_cast<float4*>(es);
  const float4* __restrict__ g4 = reinterpret_cast<const float4*>(epT);

  f32x2 acc2[4][8];                    // [pos-pair][code j]: 64 VGPRs
  #pragma unroll
  for (int pi = 0; pi < 4; ++pi)
    #pragma unroll
    for (int j = 0; j < 8; ++j) acc2[pi][j] = (f32x2)(0.f);

  dma_chunk(g4, es4 + 0 * CHUNK_F4, 0, t);     // prologue: chunks 0,1 in flight
  dma_chunk(g4, es4 + 1 * CHUNK_F4, 1, t);

  #pragma unroll 1
  for (int ch = 0; ch < NCH; ++ch) {
    asm volatile("" ::: "memory");
    if (ch < NCH - 1) {
      __builtin_amdgcn_s_waitcnt(0x0F72);      // vmcnt(2): DMA(ch) landed, DMA(ch+1) in flight
    } else {
      __builtin_amdgcn_s_waitcnt(0x0F70);      // vmcnt(0): last chunk
    }
    __builtin_amdgcn_s_barrier();              // raw barrier: no vmcnt(0) drain
    asm volatile("" ::: "memory");
    if (ch + 2 < NCH)                          // refill buffer freed at ch-1
      dma_chunk(g4, es4 + ((ch + 2) % 3) * CHUNK_F4, ch + 2, t);

    const float* __restrict__ eb = es + ((ch % 3) * CH_C * NE);
    #pragma unroll
    for (int cc = 0; cc < CH_C; ++cc) {
      const int c = ch * CH_C + cc;
      const float4 xa = *reinterpret_cast<const float4*>(&xs[c * 32 + posb]);
      const float4 xb = *reinterpret_cast<const float4*>(&xs[c * 32 + posb + 4]);
      const float4 e0 = *reinterpret_cast<const float4*>(&eb[cc * NE + kb]);
      const float4 e1 = *reinterpret_cast<const float4*>(&eb[cc * NE + kb + 4]);
      f32x2 xp[4]; f32x2 ep[4];
      xp[0][0] = xa.x; xp[0][1] = xa.y;  xp[1][0] = xa.z; xp[1][1] = xa.w;
      xp[2][0] = xb.x; xp[2][1] = xb.y;  xp[3][0] = xb.z; xp[3][1] = xb.w;
      ep[0][0] = e0.x; ep[0][1] = e0.y;  ep[1][0] = e0.z; ep[1][1] = e0.w;
      ep[2][0] = e1.x; ep[2][1] = e1.y;  ep[3][0] = e1.z; ep[3][1] = e1.w;
      #pragma unroll
      for (int pi = 0; pi < 4; ++pi) {
        #pragma unroll
        for (int jp = 0; jp < 4; ++jp) {
          // code 2jp  : e-pair LOW dword broadcast to both halves
          asm("v_pk_fma_f32 %0, %1, %2, %0 op_sel:[0,0,0] op_sel_hi:[1,0,1]"
              : "+v"(acc2[pi][2 * jp]) : "v"(xp[pi]), "v"(ep[jp]));
          // code 2jp+1: e-pair HIGH dword broadcast to both halves
          asm("v_pk_fma_f32 %0, %1, %2, %0 op_sel:[0,1,0] op_sel_hi:[1,1,1]"
              : "+v"(acc2[pi][2 * jp + 1]) : "v"(xp[pi]), "v"(ep[jp]));
        }
      }
    }
  }
  __syncthreads();                     // full drain once; safe to overlay smin/sidx

  // ---- dist + per-lane argmin (acc == -2*cross complete)
  const float4 xq0 = *reinterpret_cast<const float4*>(&xsq[posb]);
  const float4 xq1 = *reinterpret_cast<const float4*>(&xsq[posb + 4]);
  const float xqv[8] = {xq0.x, xq0.y, xq0.z, xq0.w, xq1.x, xq1.y, xq1.z, xq1.w};
  const float4 eq0 = *reinterpret_cast<const float4*>(esq + kb);
  const float4 eq1 = *reinterpret_cast<const float4*>(esq + kb + 4);
  const float esv[8] = {eq0.x, eq0.y, eq0.z, eq0.w, eq1.x, eq1.y, eq1.z, eq1.w};

  float bestd[8];
  int   besti[8];
  #pragma unroll
  for (int pi = 0; pi < 8; ++pi) {
    bestd[pi] = __builtin_inff();
    besti[pi] = 0;
    const int pr = pi >> 1, ph = pi & 1;        // pair index, half
    #pragma unroll
    for (int j = 0; j < 8; ++j) {               // ascending j: first-index-wins
      const float d = (xqv[pi] + esv[j]) + acc2[pr][j][ph];  // == (xsq+esq) - 2*cross
      if (d < bestd[pi]) { bestd[pi] = d; besti[pi] = kb + j; }
    }
  }

  // ---- combine: slot s = 16wc+q covers codes [8s,8s+8); ascending-s scan
  const int s = wc * 16 + q;
  *reinterpret_cast<float4*>(&smin[s * 32 + posb]) =
      make_float4(bestd[0], bestd[1], bestd[2], bestd[3]);
  *reinterpret_cast<float4*>(&smin[s * 32 + posb + 4]) =
      make_float4(bestd[4], bestd[5], bestd[6], bestd[7]);
  *reinterpret_cast<int4*>(&sidx[s * 32 + posb]) =
      make_int4(besti[0], besti[1], besti[2], besti[3]);
  *reinterpret_cast<int4*>(&sidx[s * 32 + posb + 4]) =
      make_int4(besti[4], besti[5], besti[6], besti[7]);
  __syncthreads();
  if (t < 32) {
    float bd = smin[t];
    int   bi = sidx[t];
    #pragma unroll
    for (int ss = 1; ss < 64; ++ss) {
      const float d = smin[ss * 32 + t];
      if (d < bd) { bd = d; bi = sidx[ss * 32 + t]; }
    }
    bcomb[t] = bi;
  }
  __syncthreads();

  // ---- gather winning codebook row (L2-hot), coalesced stores
  {
    const int pos = t & 31, cr = t >> 5;
    const int idx = bcomb[pos];
    const float* __restrict__ eq = e + idx * HD;
    #pragma unroll
    for (int i = 0; i < 8; ++i) {
      const int c = cr + 8 * i;
      out[xbase + (size_t)c * HW + pos] = eq[c];
    }
  }
}

extern "C" void kernel_launch(void* const* d_in, const int* in_sizes, int n_in,
                              void* d_out, int out_size, void* d_ws, size_t ws_size,
                              hipStream_t stream) {
  const float* x = (const float*)d_in[0];   // (64, 64, 32, 32) fp32
  const float* e = (const float*)d_in[1];   // (512, 64) fp32
  float* epT = (float*)d_ws;                // 64*512 floats: -2*e transposed
  float* esq = epT + HD * NE;               // 512 floats
  float* out = (float*)d_out;

  vq_prep_kernel<<<130, 256, 0, stream>>>(e, epT, esq);
  vq_main_kernel<<<2048, 256, 0, stream>>>(x, epT, esq, e, out);
}